// Round 1
// baseline (726.313 us; speedup 1.0000x reference)
//
#include <hip/hip_runtime.h>

#define N_POINTS 1048576
#define FEAT 64
#define RES 256
#define PLANE_ELEMS (FEAT * RES * RES)  // 4,194,304 floats = 16 MB per plane

// ---------------------------------------------------------------------------
// Transpose [C=64, H*W=65536] -> [H*W, C] (channels-last) via LDS tile.
// One block handles 64 positions x 64 channels. Reads coalesced along p,
// writes coalesced along c. tile padded +1 to kill bank conflicts.
// ---------------------------------------------------------------------------
__global__ __launch_bounds__(256) void transpose_planes(
    const float* __restrict__ pxy, const float* __restrict__ pxz,
    const float* __restrict__ pyz, float* __restrict__ dst) {
  __shared__ float tile[64][65];
  const int plane = blockIdx.y;
  const float* src = (plane == 0) ? pxy : ((plane == 1) ? pxz : pyz);
  float* out = dst + (size_t)plane * PLANE_ELEMS;
  const int p0 = blockIdx.x * 64;
  const int tid = threadIdx.x;
#pragma unroll
  for (int k = 0; k < 16; ++k) {
    int l = k * 256 + tid;
    int c = l >> 6;    // channel
    int pp = l & 63;   // position within tile
    tile[pp][c] = src[(size_t)c * (RES * RES) + p0 + pp];
  }
  __syncthreads();
#pragma unroll
  for (int k = 0; k < 16; ++k) {
    int l = k * 256 + tid;
    int pp = l >> 6;
    int c = l & 63;
    out[(size_t)(p0 + pp) * FEAT + c] = tile[pp][c];
  }
}

// ---------------------------------------------------------------------------
// Main sampling kernel: 16 threads per point, each thread owns 4 channels
// (float4). Corner loads are 16 lanes x 16 B = 256 B contiguous, all useful.
// ---------------------------------------------------------------------------
__device__ __forceinline__ void sample_plane(const float* __restrict__ tp,
                                             float u, float v, int c4,
                                             float4& acc) {
  float ix = (u + 1.0f) * 0.5f * (float)(RES - 1);
  float iy = (v + 1.0f) * 0.5f * (float)(RES - 1);
  float fx0 = floorf(ix), fy0 = floorf(iy);
  // weights from UNCLAMPED floor coords (matches reference)
  float wx1 = ix - fx0, wy1 = iy - fy0;
  float wx0 = fx0 + 1.0f - ix, wy0 = fy0 + 1.0f - iy;
  int x0 = min(max((int)fx0, 0), RES - 1);
  int y0 = min(max((int)fy0, 0), RES - 1);
  int x1 = min(max((int)fx0 + 1, 0), RES - 1);
  int y1 = min(max((int)fy0 + 1, 0), RES - 1);

  const float4 v00 = *(const float4*)(tp + (size_t)(y0 * RES + x0) * FEAT + c4);
  const float4 v01 = *(const float4*)(tp + (size_t)(y0 * RES + x1) * FEAT + c4);
  const float4 v10 = *(const float4*)(tp + (size_t)(y1 * RES + x0) * FEAT + c4);
  const float4 v11 = *(const float4*)(tp + (size_t)(y1 * RES + x1) * FEAT + c4);

  float w00 = wx0 * wy0, w01 = wx1 * wy0, w10 = wx0 * wy1, w11 = wx1 * wy1;
  acc.x += v00.x * w00 + v01.x * w01 + v10.x * w10 + v11.x * w11;
  acc.y += v00.y * w00 + v01.y * w01 + v10.y * w10 + v11.y * w11;
  acc.z += v00.z * w00 + v01.z * w01 + v10.z * w10 + v11.z * w11;
  acc.w += v00.w * w00 + v01.w * w01 + v10.w * w10 + v11.w * w11;
}

__global__ __launch_bounds__(256) void triplane_sample(
    const float* __restrict__ x, const float* __restrict__ tps,
    float* __restrict__ out) {
  int t = blockIdx.x * 256 + threadIdx.x;
  int n = t >> 4;          // point index (16 threads/point)
  int c4 = (t & 15) << 2;  // channel group base

  float px = x[n * 3 + 0];
  float py = x[n * 3 + 1];
  float pz = x[n * 3 + 2];

  float4 acc = make_float4(0.f, 0.f, 0.f, 0.f);
  sample_plane(tps, px, py, c4, acc);                    // plane_xy: (x, y)
  sample_plane(tps + PLANE_ELEMS, px, pz, c4, acc);      // plane_xz: (x, z)
  sample_plane(tps + 2 * PLANE_ELEMS, py, pz, c4, acc);  // plane_yz: (y, z)

  const float s = 1.0f / 3.0f;
  float4 r = make_float4(acc.x * s, acc.y * s, acc.z * s, acc.w * s);
  *(float4*)(out + (size_t)n * FEAT + c4) = r;
}

// ---------------------------------------------------------------------------
// Fallback: direct gather from native [C,H,W] layout (only if ws too small).
// ---------------------------------------------------------------------------
__device__ __forceinline__ float sample_one(const float* __restrict__ pc,
                                            float u, float v) {
  float ix = (u + 1.0f) * 0.5f * (float)(RES - 1);
  float iy = (v + 1.0f) * 0.5f * (float)(RES - 1);
  float fx0 = floorf(ix), fy0 = floorf(iy);
  float wx1 = ix - fx0, wy1 = iy - fy0;
  float wx0 = fx0 + 1.0f - ix, wy0 = fy0 + 1.0f - iy;
  int x0 = min(max((int)fx0, 0), RES - 1);
  int y0 = min(max((int)fy0, 0), RES - 1);
  int x1 = min(max((int)fx0 + 1, 0), RES - 1);
  int y1 = min(max((int)fy0 + 1, 0), RES - 1);
  return pc[y0 * RES + x0] * (wx0 * wy0) + pc[y0 * RES + x1] * (wx1 * wy0) +
         pc[y1 * RES + x0] * (wx0 * wy1) + pc[y1 * RES + x1] * (wx1 * wy1);
}

__global__ __launch_bounds__(256) void triplane_direct(
    const float* __restrict__ x, const float* __restrict__ pxy,
    const float* __restrict__ pxz, const float* __restrict__ pyz,
    float* __restrict__ out) {
  int t = blockIdx.x * 256 + threadIdx.x;
  int n = t >> 6;
  int c = t & 63;
  float px = x[n * 3 + 0];
  float py = x[n * 3 + 1];
  float pz = x[n * 3 + 2];
  const size_t cs = (size_t)c * (RES * RES);
  float acc = sample_one(pxy + cs, px, py) + sample_one(pxz + cs, px, pz) +
              sample_one(pyz + cs, py, pz);
  out[(size_t)n * FEAT + c] = acc * (1.0f / 3.0f);
}

extern "C" void kernel_launch(void* const* d_in, const int* in_sizes, int n_in,
                              void* d_out, int out_size, void* d_ws,
                              size_t ws_size, hipStream_t stream) {
  const float* x   = (const float*)d_in[0];
  const float* pxy = (const float*)d_in[1];
  const float* pxz = (const float*)d_in[2];
  const float* pyz = (const float*)d_in[3];
  float* out = (float*)d_out;

  const size_t need = (size_t)3 * PLANE_ELEMS * sizeof(float);  // 48 MB
  if (ws_size >= need) {
    float* tps = (float*)d_ws;
    dim3 tgrid(RES * RES / 64, 3);
    transpose_planes<<<tgrid, 256, 0, stream>>>(pxy, pxz, pyz, tps);
    triplane_sample<<<(N_POINTS * 16) / 256, 256, 0, stream>>>(x, tps, out);
  } else {
    triplane_direct<<<(N_POINTS * 64) / 256, 256, 0, stream>>>(x, pxy, pxz,
                                                               pyz, out);
  }
}

// Round 3
// 499.707 us; speedup vs baseline: 1.4535x; 1.4535x over previous
//
#include <hip/hip_runtime.h>

#define N_POINTS 1048576
#define FEAT 64
#define RES 256
#define PLANE_ELEMS (FEAT * RES * RES)  // elements per plane (4.19M)

typedef unsigned short ushort_t;
typedef float v4f __attribute__((ext_vector_type(4)));  // native vec for nt-store

// round-to-nearest-even float -> bf16 bits
__device__ __forceinline__ ushort_t f2bf(float f) {
  unsigned u = __float_as_uint(f);
  unsigned r = u + 0x7FFFu + ((u >> 16) & 1u);
  return (ushort_t)(r >> 16);
}

// ---------------------------------------------------------------------------
// Transpose + convert: fp32 [C=64, H*W] -> bf16 [H*W, C=64].
// Tile 64 positions x 64 channels per block. float4 loads along p,
// ushort8 (16B) stores along c. LDS rows padded to 72 ushorts (144 B,
// 16B-aligned) for ds_read_b128.
// ---------------------------------------------------------------------------
__global__ __launch_bounds__(256) void transpose_bf16(
    const float* __restrict__ pxy, const float* __restrict__ pxz,
    const float* __restrict__ pyz, ushort_t* __restrict__ dst) {
  __shared__ ushort_t tile[64][72];  // [p][c]
  const int plane = blockIdx.y;
  const float* src = (plane == 0) ? pxy : ((plane == 1) ? pxz : pyz);
  ushort_t* out = dst + (size_t)plane * PLANE_ELEMS;
  const int p0 = blockIdx.x * 64;
  const int tid = threadIdx.x;
#pragma unroll
  for (int k = 0; k < 4; ++k) {
    int c = (tid >> 4) + k * 16;  // 0..63
    int pp = (tid & 15) * 4;      // 0..60, float4-aligned
    float4 v = *(const float4*)(src + (size_t)c * (RES * RES) + p0 + pp);
    tile[pp + 0][c] = f2bf(v.x);
    tile[pp + 1][c] = f2bf(v.y);
    tile[pp + 2][c] = f2bf(v.z);
    tile[pp + 3][c] = f2bf(v.w);
  }
  __syncthreads();
#pragma unroll
  for (int k = 0; k < 2; ++k) {
    int idx = k * 256 + tid;
    int pp = idx >> 3;            // 0..63
    int c8 = (idx & 7) * 8;       // 0..56
    uint4 v = *(const uint4*)&tile[pp][c8];  // 16B-aligned LDS read
    *(uint4*)(out + (size_t)(p0 + pp) * FEAT + c8) = v;
  }
}

// ---------------------------------------------------------------------------
// Sampling: 8 lanes/point, each lane owns 8 channels (ushort8 = 16 B).
// Corner gather = 8 lanes x 16 B = 128 B contiguous (2 cache lines).
// ---------------------------------------------------------------------------
__device__ __forceinline__ void unpack_fma(uint4 v, float w, float* acc) {
  // 8 bf16 -> fp32 via shift/mask, then FMA with weight w
  acc[0] = fmaf(__uint_as_float(v.x << 16), w, acc[0]);
  acc[1] = fmaf(__uint_as_float(v.x & 0xFFFF0000u), w, acc[1]);
  acc[2] = fmaf(__uint_as_float(v.y << 16), w, acc[2]);
  acc[3] = fmaf(__uint_as_float(v.y & 0xFFFF0000u), w, acc[3]);
  acc[4] = fmaf(__uint_as_float(v.z << 16), w, acc[4]);
  acc[5] = fmaf(__uint_as_float(v.z & 0xFFFF0000u), w, acc[5]);
  acc[6] = fmaf(__uint_as_float(v.w << 16), w, acc[6]);
  acc[7] = fmaf(__uint_as_float(v.w & 0xFFFF0000u), w, acc[7]);
}

__device__ __forceinline__ void sample_plane(const ushort_t* __restrict__ tp,
                                             float u, float v, int c8,
                                             float* acc) {
  float ix = (u + 1.0f) * 0.5f * (float)(RES - 1);
  float iy = (v + 1.0f) * 0.5f * (float)(RES - 1);
  float fx0 = floorf(ix), fy0 = floorf(iy);
  // weights from UNCLAMPED floor coords (reference semantics)
  float wx1 = ix - fx0, wy1 = iy - fy0;
  float wx0 = fx0 + 1.0f - ix, wy0 = fy0 + 1.0f - iy;
  int x0 = min(max((int)fx0, 0), RES - 1);
  int y0 = min(max((int)fy0, 0), RES - 1);
  int x1 = min(max((int)fx0 + 1, 0), RES - 1);
  int y1 = min(max((int)fy0 + 1, 0), RES - 1);

  const uint4 v00 = *(const uint4*)(tp + (size_t)(y0 * RES + x0) * FEAT + c8);
  const uint4 v01 = *(const uint4*)(tp + (size_t)(y0 * RES + x1) * FEAT + c8);
  const uint4 v10 = *(const uint4*)(tp + (size_t)(y1 * RES + x0) * FEAT + c8);
  const uint4 v11 = *(const uint4*)(tp + (size_t)(y1 * RES + x1) * FEAT + c8);

  unpack_fma(v00, wx0 * wy0, acc);
  unpack_fma(v01, wx1 * wy0, acc);
  unpack_fma(v10, wx0 * wy1, acc);
  unpack_fma(v11, wx1 * wy1, acc);
}

__global__ __launch_bounds__(256) void triplane_sample_bf16(
    const float* __restrict__ x, const ushort_t* __restrict__ tps,
    float* __restrict__ out) {
  int t = blockIdx.x * 256 + threadIdx.x;
  int n = t >> 3;         // point index (8 threads/point)
  int c8 = (t & 7) << 3;  // channel group base

  // streaming reads of x: nontemporal to avoid L2 pollution
  float px = __builtin_nontemporal_load(x + n * 3 + 0);
  float py = __builtin_nontemporal_load(x + n * 3 + 1);
  float pz = __builtin_nontemporal_load(x + n * 3 + 2);

  float acc[8] = {0.f, 0.f, 0.f, 0.f, 0.f, 0.f, 0.f, 0.f};
  sample_plane(tps, px, py, c8, acc);                    // plane_xy: (x, y)
  sample_plane(tps + PLANE_ELEMS, px, pz, c8, acc);      // plane_xz: (x, z)
  sample_plane(tps + 2 * PLANE_ELEMS, py, pz, c8, acc);  // plane_yz: (y, z)

  const float s = 1.0f / 3.0f;
  v4f lo = {acc[0] * s, acc[1] * s, acc[2] * s, acc[3] * s};
  v4f hi = {acc[4] * s, acc[5] * s, acc[6] * s, acc[7] * s};
  float* o = out + (size_t)n * FEAT + c8;
  __builtin_nontemporal_store(lo, (v4f*)o);
  __builtin_nontemporal_store(hi, (v4f*)(o + 4));
}

// ---------------------------------------------------------------------------
// Fallback: direct gather from native [C,H,W] layout (only if ws too small).
// ---------------------------------------------------------------------------
__device__ __forceinline__ float sample_one(const float* __restrict__ pc,
                                            float u, float v) {
  float ix = (u + 1.0f) * 0.5f * (float)(RES - 1);
  float iy = (v + 1.0f) * 0.5f * (float)(RES - 1);
  float fx0 = floorf(ix), fy0 = floorf(iy);
  float wx1 = ix - fx0, wy1 = iy - fy0;
  float wx0 = fx0 + 1.0f - ix, wy0 = fy0 + 1.0f - iy;
  int x0 = min(max((int)fx0, 0), RES - 1);
  int y0 = min(max((int)fy0, 0), RES - 1);
  int x1 = min(max((int)fx0 + 1, 0), RES - 1);
  int y1 = min(max((int)fy0 + 1, 0), RES - 1);
  return pc[y0 * RES + x0] * (wx0 * wy0) + pc[y0 * RES + x1] * (wx1 * wy0) +
         pc[y1 * RES + x0] * (wx0 * wy1) + pc[y1 * RES + x1] * (wx1 * wy1);
}

__global__ __launch_bounds__(256) void triplane_direct(
    const float* __restrict__ x, const float* __restrict__ pxy,
    const float* __restrict__ pxz, const float* __restrict__ pyz,
    float* __restrict__ out) {
  int t = blockIdx.x * 256 + threadIdx.x;
  int n = t >> 6;
  int c = t & 63;
  float px = x[n * 3 + 0];
  float py = x[n * 3 + 1];
  float pz = x[n * 3 + 2];
  const size_t cs = (size_t)c * (RES * RES);
  float acc = sample_one(pxy + cs, px, py) + sample_one(pxz + cs, px, pz) +
              sample_one(pyz + cs, py, pz);
  out[(size_t)n * FEAT + c] = acc * (1.0f / 3.0f);
}

extern "C" void kernel_launch(void* const* d_in, const int* in_sizes, int n_in,
                              void* d_out, int out_size, void* d_ws,
                              size_t ws_size, hipStream_t stream) {
  const float* x   = (const float*)d_in[0];
  const float* pxy = (const float*)d_in[1];
  const float* pxz = (const float*)d_in[2];
  const float* pyz = (const float*)d_in[3];
  float* out = (float*)d_out;

  const size_t need = (size_t)3 * PLANE_ELEMS * sizeof(ushort_t);  // 24 MB
  if (ws_size >= need) {
    ushort_t* tps = (ushort_t*)d_ws;
    dim3 tgrid(RES * RES / 64, 3);
    transpose_bf16<<<tgrid, 256, 0, stream>>>(pxy, pxz, pyz, tps);
    triplane_sample_bf16<<<(N_POINTS * 8) / 256, 256, 0, stream>>>(x, tps, out);
  } else {
    triplane_direct<<<(N_POINTS * 64) / 256, 256, 0, stream>>>(x, pxy, pxz,
                                                               pyz, out);
  }
}